// Round 2
// baseline (2919.522 us; speedup 1.0000x reference)
//
#include <hip/hip_runtime.h>

typedef unsigned short u16;
typedef __attribute__((ext_vector_type(8))) short short8;
typedef __attribute__((ext_vector_type(4))) float floatx4;
typedef _Float16 half8 __attribute__((ext_vector_type(8)));
typedef _Float16 half2v __attribute__((ext_vector_type(2)));

// ---------- helpers ----------
__device__ __forceinline__ float bf2f(u16 v) { return __uint_as_float(((unsigned)v) << 16); }
__device__ __forceinline__ u16 f2bf(float f) {
    unsigned u = __float_as_uint(f);
    unsigned r = (u + 0x7FFFu + ((u >> 16) & 1u)) >> 16;
    return (u16)r;
}
__device__ __forceinline__ float sigm_(float x) { return 1.f / (1.f + __expf(-x)); }
__device__ __forceinline__ float tanh_(float x) {
    x = fminf(fmaxf(x, -15.f), 15.f);
    float e = __expf(2.f * x);
    return (e - 1.f) / (e + 1.f);
}

// B=32, C=512, H=6, W=40, NC=97, L=26, T=27

// ---------- dtype sniffing: flag=1 if inputs are fp32, 0 if bf16 ----------
__global__ void sniff_k(const void* __restrict__ feat_raw, int* __restrict__ flag) {
    if (threadIdx.x == 0 && blockIdx.x == 0) {
        const u16* p = (const u16*)feat_raw;
        int insane = 0;
        #pragma unroll
        for (int i = 0; i < 32; i += 2) {   // even u16 idx: fp32 low mantissa halves
            float x = bf2f(p[i]);
            float a = fabsf(x);
            if (!(a <= 1000.f)) insane = 1;               // huge or NaN
            if (x != 0.f && a < 1e-8f) insane = 1;        // absurdly tiny
        }
        *flag = insane;
    }
}

// canonical bf16 copy of a float tensor (either fp32 or bf16 source)
__global__ __launch_bounds__(256) void canon_k(const void* __restrict__ src, u16* __restrict__ dst,
                                               int n, const int* __restrict__ flag) {
    int i = blockIdx.x * 256 + threadIdx.x;
    if (i >= n) return;
    if (*flag) dst[i] = f2bf(((const float*)src)[i]);
    else       dst[i] = ((const u16*)src)[i];
}

// canonical fp32 copy (for valid_ratios: exact mask arithmetic)
__global__ __launch_bounds__(64) void canonf_k(const void* __restrict__ src, float* __restrict__ dst,
                                               int n, const int* __restrict__ flag) {
    int i = blockIdx.x * 64 + threadIdx.x;
    if (i >= n) return;
    dst[i] = (*flag) ? ((const float*)src)[i] : bf2f(((const u16*)src)[i]);
}

// ---------- prep kernels ----------

// fc (B,C,6,40) bf16 -> featv (B,40,C) bf16 (max over H)
__global__ __launch_bounds__(256) void featv_k(const u16* __restrict__ fc, u16* __restrict__ featv) {
    int idx = blockIdx.x * 256 + threadIdx.x;   // (b*40+w)*512 + c
    int c = idx & 511;
    int r = idx >> 9;     // b*40 + w
    int w = r % 40, b = r / 40;
    float mx = -1e30f;
    const u16* fp = fc + ((long)(b * 512 + c) * 6) * 40 + w;
    #pragma unroll
    for (int h = 0; h < 6; h++) mx = fmaxf(mx, bf2f(fp[h * 40]));
    featv[idx] = f2bf(mx);
}

// fc (B,C,6,40) -> featP (B,8,42,C) bf16 zero-padded NHWC
__global__ __launch_bounds__(256) void padfeat_k(const u16* __restrict__ fc, u16* __restrict__ featP) {
    int idx = blockIdx.x * 256 + threadIdx.x;
    int c = idx & 511;
    int r = idx >> 9;         // (b*8+hp)*42+wp
    int wp = r % 42; int r2 = r / 42;
    int hp = r2 & 7; int b = r2 >> 3;
    u16 v = 0;
    if (hp >= 1 && hp <= 6 && wp >= 1 && wp <= 40)
        v = fc[((long)(b * 512 + c) * 6 + (hp - 1)) * 40 + (wp - 1)];
    featP[idx] = v;
}

// k_W (Co,Ci,3,3) raw -> W2 (Co, (kh*3+kw)*512+ci) bf16, dtype-aware
__global__ __launch_bounds__(256) void w2_k(const void* __restrict__ kW, u16* __restrict__ W2,
                                            const int* __restrict__ flag) {
    int idx = blockIdx.x * 256 + threadIdx.x;   // co*4608 + (kh*3+kw)*512 + ci
    int co = idx / 4608;
    int r = idx % 4608;
    int kh = r / 1536;
    int r2 = r % 1536;
    int kw = r2 / 512;
    int ci = r2 & 511;
    long si = ((long)(co * 512 + ci) * 3 + kh) * 3 + kw;
    W2[idx] = (*flag) ? f2bf(((const float*)kW)[si]) : ((const u16*)kW)[si];
}

// Whh (2048,512) raw -> Wq f16, layout Wq[((k8*2048)+n)*8 + j] = Whh[n][k8*8+j]
__global__ __launch_bounds__(256) void wq_k(const void* __restrict__ W, _Float16* __restrict__ Wq,
                                            const int* __restrict__ flag) {
    int idx = blockIdx.x * 256 + threadIdx.x;   // k8*2048 + n  (131072 total)
    int n = idx & 2047;
    int k8 = idx >> 11;
    int fl = *flag;
    _Float16* dst = Wq + (long)idx * 8;
    #pragma unroll
    for (int j = 0; j < 8; j++) {
        long si = (long)n * 512 + k8 * 8 + j;
        float v = fl ? ((const float*)W)[si] : bf2f(((const u16*)W)[si]);
        dst[j] = (_Float16)v;
    }
}

// ---------- NT GEMM: C(MxN,f32) = A(MxK,bf16,lda) * B(NxK,bf16)^T + bias ----------
__global__ __launch_bounds__(256) void gemm_nt_f32(
    const u16* __restrict__ A, int lda,
    const u16* __restrict__ Bw,
    const u16* __restrict__ bias0, const u16* __restrict__ bias1,
    float* __restrict__ C, int M, int N, int K, int ldc)
{
    __shared__ __align__(16) u16 As[64][40];
    __shared__ __align__(16) u16 Bs[64][40];
    const int tid = threadIdx.x;
    const int bn = blockIdx.x, bm = blockIdx.y;
    const int l = tid & 63, wid = tid >> 6;
    const int wm = wid >> 1, wn = wid & 1;
    const int lr = tid >> 2, lc = (tid & 3) * 8;
    const int l15 = l & 15, lq = l >> 4;

    floatx4 acc00 = (floatx4)(0.f), acc01 = (floatx4)(0.f), acc10 = (floatx4)(0.f), acc11 = (floatx4)(0.f);

    int am = bm * 64 + lr; if (am > M - 1) am = M - 1;
    const u16* Ap = A + (long)am * lda + lc;
    const u16* Bp = Bw + (long)(bn * 64 + lr) * K + lc;

    for (int k0 = 0; k0 < K; k0 += 32) {
        *(short8*)&As[lr][lc] = *(const short8*)(Ap + k0);
        *(short8*)&Bs[lr][lc] = *(const short8*)(Bp + k0);
        __syncthreads();
        short8 af0 = *(const short8*)&As[wm * 32 + l15][lq * 8];
        short8 af1 = *(const short8*)&As[wm * 32 + 16 + l15][lq * 8];
        short8 bf0 = *(const short8*)&Bs[wn * 32 + l15][lq * 8];
        short8 bf1 = *(const short8*)&Bs[wn * 32 + 16 + l15][lq * 8];
        acc00 = __builtin_amdgcn_mfma_f32_16x16x32_bf16(af0, bf0, acc00, 0, 0, 0);
        acc01 = __builtin_amdgcn_mfma_f32_16x16x32_bf16(af0, bf1, acc01, 0, 0, 0);
        acc10 = __builtin_amdgcn_mfma_f32_16x16x32_bf16(af1, bf0, acc10, 0, 0, 0);
        acc11 = __builtin_amdgcn_mfma_f32_16x16x32_bf16(af1, bf1, acc11, 0, 0, 0);
        __syncthreads();
    }
    floatx4 accs[2][2] = {{acc00, acc01}, {acc10, acc11}};
    #pragma unroll
    for (int i = 0; i < 2; i++)
        #pragma unroll
        for (int j = 0; j < 2; j++)
            #pragma unroll
            for (int r = 0; r < 4; r++) {
                int gm = bm * 64 + wm * 32 + i * 16 + lq * 4 + r;
                int gn = bn * 64 + wn * 32 + j * 16 + l15;
                if (gm < M) {
                    float v = accs[i][j][r];
                    if (bias0) v += bf2f(bias0[gn]);
                    if (bias1) v += bf2f(bias1[gn]);
                    C[(long)gm * ldc + gn] = v;
                }
            }
}

// ---------- conv3x3 as implicit-im2col NT GEMM: out kmap (B*240, 512) bf16 ----------
__global__ __launch_bounds__(256) void conv_gemm(
    const u16* __restrict__ featP, const u16* __restrict__ W2,
    const u16* __restrict__ kb, u16* __restrict__ kmap)
{
    __shared__ __align__(16) u16 As[64][40];
    __shared__ __align__(16) u16 Bs[64][40];
    const int tid = threadIdx.x;
    const int bn = blockIdx.x, bm = blockIdx.y;
    const int l = tid & 63, wid = tid >> 6;
    const int wm = wid >> 1, wn = wid & 1;
    const int lr = tid >> 2, lc = (tid & 3) * 8;
    const int l15 = l & 15, lq = l >> 4;

    floatx4 acc00 = (floatx4)(0.f), acc01 = (floatx4)(0.f), acc10 = (floatx4)(0.f), acc11 = (floatx4)(0.f);

    int gm = bm * 64 + lr;             // < 7680 always
    int b = gm / 240;
    int hw = gm % 240;
    int h = hw / 40, w = hw % 40;
    const u16* fb = featP + (long)(b * 8) * 42 * 512;
    const u16* Bp = W2 + (long)(bn * 64 + lr) * 4608 + lc;

    for (int k0 = 0; k0 < 4608; k0 += 32) {
        int kh = k0 / 1536;
        int kw = (k0 % 1536) / 512;
        int ci0 = k0 & 511;
        const u16* ap = fb + ((long)((h + kh) * 42 + (w + kw))) * 512 + ci0 + lc;
        *(short8*)&As[lr][lc] = *(const short8*)ap;
        *(short8*)&Bs[lr][lc] = *(const short8*)(Bp + k0);
        __syncthreads();
        short8 af0 = *(const short8*)&As[wm * 32 + l15][lq * 8];
        short8 af1 = *(const short8*)&As[wm * 32 + 16 + l15][lq * 8];
        short8 bf0 = *(const short8*)&Bs[wn * 32 + l15][lq * 8];
        short8 bf1 = *(const short8*)&Bs[wn * 32 + 16 + l15][lq * 8];
        acc00 = __builtin_amdgcn_mfma_f32_16x16x32_bf16(af0, bf0, acc00, 0, 0, 0);
        acc01 = __builtin_amdgcn_mfma_f32_16x16x32_bf16(af0, bf1, acc01, 0, 0, 0);
        acc10 = __builtin_amdgcn_mfma_f32_16x16x32_bf16(af1, bf0, acc10, 0, 0, 0);
        acc11 = __builtin_amdgcn_mfma_f32_16x16x32_bf16(af1, bf1, acc11, 0, 0, 0);
        __syncthreads();
    }
    floatx4 accs[2][2] = {{acc00, acc01}, {acc10, acc11}};
    #pragma unroll
    for (int i = 0; i < 2; i++)
        #pragma unroll
        for (int j = 0; j < 2; j++)
            #pragma unroll
            for (int r = 0; r < 4; r++) {
                int om = bm * 64 + wm * 32 + i * 16 + lq * 4 + r;
                int on = bn * 64 + wn * 32 + j * 16 + l15;
                float v = accs[i][j][r] + bf2f(kb[on]);
                kmap[(long)om * 512 + on] = f2bf(v);
            }
}

// ---------- LSTM recurrence: 1 block per batch element ----------
__global__ __launch_bounds__(256) void lstm_rec(
    const float* __restrict__ xpre, const _Float16* __restrict__ Wq,
    u16* __restrict__ seq_out, float* __restrict__ f32_out,
    int T, int f32_ld)
{
    const int b = blockIdx.x, tid = threadIdx.x;
    __shared__ __align__(16) _Float16 hS[512];
    hS[tid] = (_Float16)0.f;
    hS[tid + 256] = (_Float16)0.f;
    float c0 = 0.f, c1 = 0.f;
    __syncthreads();
    for (int t = 0; t < T; t++) {
        const float* xp = xpre + ((long)b * T + t) * 2048;
        float g[8];
        #pragma unroll
        for (int j = 0; j < 8; j++) g[j] = xp[tid + 256 * j];
        for (int k8 = 0; k8 < 64; k8++) {
            half8 hv = *(const half8*)&hS[k8 * 8];
            half2v h0 = __builtin_shufflevector(hv, hv, 0, 1);
            half2v h1 = __builtin_shufflevector(hv, hv, 2, 3);
            half2v h2 = __builtin_shufflevector(hv, hv, 4, 5);
            half2v h3 = __builtin_shufflevector(hv, hv, 6, 7);
            const _Float16* wp = Wq + ((long)k8 * 2048 + tid) * 8;
            #pragma unroll
            for (int j = 0; j < 8; j++) {
                half8 wv = *(const half8*)(wp + 2048 * j);
                g[j] = __builtin_amdgcn_fdot2(h0, __builtin_shufflevector(wv, wv, 0, 1), g[j], false);
                g[j] = __builtin_amdgcn_fdot2(h1, __builtin_shufflevector(wv, wv, 2, 3), g[j], false);
                g[j] = __builtin_amdgcn_fdot2(h2, __builtin_shufflevector(wv, wv, 4, 5), g[j], false);
                g[j] = __builtin_amdgcn_fdot2(h3, __builtin_shufflevector(wv, wv, 6, 7), g[j], false);
            }
        }
        c0 = sigm_(g[2]) * c0 + sigm_(g[0]) * tanh_(g[4]);
        float h0v = sigm_(g[6]) * tanh_(c0);
        c1 = sigm_(g[3]) * c1 + sigm_(g[1]) * tanh_(g[5]);
        float h1v = sigm_(g[7]) * tanh_(c1);
        __syncthreads();
        hS[tid] = (_Float16)h0v;
        hS[tid + 256] = (_Float16)h1v;
        u16* so = seq_out + ((long)b * T + t) * 512;
        so[tid] = f2bf(h0v);
        so[tid + 256] = f2bf(h1v);
        if (f32_out) {
            float* fo = f32_out + ((long)b * T + t) * f32_ld;
            fo[tid] = h0v;
            fo[tid + 256] = h1v;
        }
        __syncthreads();
    }
}

// ---------- token build: tok (B,27,512) bf16 ----------
__global__ __launch_bounds__(256) void tok_k(
    const float* __restrict__ holf, const u16* __restrict__ cemb,
    const int* __restrict__ label, u16* __restrict__ tok)
{
    int idx = blockIdx.x * 256 + threadIdx.x;   // m*512 + c, m = b*27+t
    int c = idx & 511;
    int m = idx >> 9;
    int b = m / 27, t = m % 27;
    float v;
    if (t == 0) v = holf[(long)b * 512 + c];
    else v = bf2f(cemb[(long)label[b * 26 + (t - 1)] * 512 + c]);
    tok[idx] = f2bf(v);
}

// ---------- fused score: tanh-dot + mask + softmax -> aw (B,27,240) f32 ----------
__global__ __launch_bounds__(256) void score_k(
    const float* __restrict__ q, const u16* __restrict__ kmap,
    const u16* __restrict__ sW, const u16* __restrict__ sb,
    const float* __restrict__ vr, float* __restrict__ aw)
{
    int bt = blockIdx.x;
    int b = bt / 27;
    int tid = threadIdx.x;
    __shared__ float qs[512];
    __shared__ float ss[512];
    __shared__ float red[256];
    qs[tid] = q[(long)bt * 512 + tid];
    qs[tid + 256] = q[(long)bt * 512 + tid + 256];
    ss[tid] = bf2f(sW[tid]);
    ss[tid + 256] = bf2f(sW[tid + 256]);
    __syncthreads();
    float sc = -INFINITY;
    float ex = 0.f;
    if (tid < 240) {
        const u16* kp = kmap + ((long)b * 240 + tid) * 512;
        float acc = 0.f;
        for (int c = 0; c < 512; c++) {
            float x = bf2f(kp[c]) + qs[c];
            acc = fmaf(ss[c], tanh_(x), acc);
        }
        acc += bf2f(sb[0]);
        float r = vr[b];
        int vw = (int)ceilf(40.f * r);
        if (vw > 40) vw = 40;
        int wcol = tid % 40;
        sc = (wcol >= vw) ? -INFINITY : acc;
    }
    red[tid] = sc;
    __syncthreads();
    for (int s = 128; s > 0; s >>= 1) {
        if (tid < s) red[tid] = fmaxf(red[tid], red[tid + s]);
        __syncthreads();
    }
    float mx = red[0];
    __syncthreads();
    if (tid < 240) ex = (sc == -INFINITY) ? 0.f : __expf(sc - mx);
    red[tid] = ex;
    __syncthreads();
    for (int s = 128; s > 0; s >>= 1) {
        if (tid < s) red[tid] += red[tid + s];
        __syncthreads();
    }
    float inv = 1.f / red[0];
    if (tid < 240) aw[(long)bt * 240 + tid] = ex * inv;
}

// ---------- attn_feat -> concat cols [512,1024) f32 ----------
__global__ __launch_bounds__(256) void attn_k(
    const u16* __restrict__ fc, const float* __restrict__ aw,
    float* __restrict__ concat)
{
    int b = blockIdx.x >> 3;
    int cc = (blockIdx.x & 7) * 64;
    int tid = threadIdx.x;
    __shared__ float awS[27 * 240];
    __shared__ u16 fS[64 * 240];
    for (int i = tid; i < 27 * 240; i += 256) awS[i] = aw[(long)b * 27 * 240 + i];
    for (int i = tid; i < 64 * 240; i += 256) fS[i] = fc[((long)b * 512 + cc) * 240 + i];
    __syncthreads();
    for (int item = tid; item < 64 * 27; item += 256) {
        int c = item / 27, t = item % 27;
        const u16* fp = &fS[c * 240];
        const float* ap = &awS[t * 240];
        float acc = 0.f;
        for (int hw = 0; hw < 240; hw++) acc = fmaf(bf2f(fp[hw]), ap[hw], acc);
        concat[((long)(b * 27 + t)) * 1536 + 512 + cc + c] = acc;
    }
}

// ---------- holistic broadcast -> concat cols [1024,1536) ----------
__global__ __launch_bounds__(256) void holfill_k(const float* __restrict__ holf, float* __restrict__ concat) {
    int idx = blockIdx.x * 256 + threadIdx.x;   // m*512 + c
    int c = idx & 511;
    int m = idx >> 9;
    int b = m / 27;
    concat[(long)m * 1536 + 1024 + c] = holf[(long)b * 512 + c];
}

// ---------- prediction + slice: out (B,26,97), dtype per flag ----------
__global__ __launch_bounds__(256) void pred_k(
    const float* __restrict__ concat, const u16* __restrict__ pW,
    const u16* __restrict__ pb, void* __restrict__ out, const int* __restrict__ flag)
{
    int m0 = blockIdx.x * 4;
    int tid = threadIdx.x;
    const int fl = *flag;
    __shared__ float aS[4][1536];
    for (int i = tid; i < 4 * 1536; i += 256)
        aS[i / 1536][i % 1536] = concat[(long)(m0 + i / 1536) * 1536 + (i % 1536)];
    __syncthreads();
    int r = tid >> 6;
    int nb = tid & 63;
    int m = m0 + r;
    int b = m / 27, t = m % 27;
    for (int n = nb; n < 97; n += 64) {
        const u16* wp = pW + (long)n * 1536;
        float acc = 0.f;
        for (int k = 0; k < 1536; k++) acc = fmaf(aS[r][k], bf2f(wp[k]), acc);
        acc += bf2f(pb[n]);
        if (t > 0) {
            long o = ((long)(b * 26 + (t - 1))) * 97 + n;
            if (fl) ((float*)out)[o] = acc;
            else    ((u16*)out)[o] = f2bf(acc);
        }
    }
}

// ---------- launch ----------
extern "C" void kernel_launch(void* const* d_in, const int* in_sizes, int n_in,
                              void* d_out, int out_size, void* d_ws, size_t ws_size,
                              hipStream_t stream) {
    (void)in_sizes; (void)n_in; (void)out_size; (void)ws_size;
    const void* feat_r   = d_in[0];
    const int*  label    = (const int*)d_in[1];
    const void* vr_r     = d_in[2];
    const void* e0_Wih_r = d_in[3];
    const void* e0_Whh_r = d_in[4];
    const void* e0_bih_r = d_in[5];
    const void* e0_bhh_r = d_in[6];
    const void* e1_Wih_r = d_in[7];
    const void* e1_Whh_r = d_in[8];
    const void* e1_bih_r = d_in[9];
    const void* e1_bhh_r = d_in[10];
    const void* enc_W_r  = d_in[11];
    const void* enc_b_r  = d_in[12];
    const void* q_W_r    = d_in[13];
    const void* q_b_r    = d_in[14];
    const void* k_W_r    = d_in[15];
    const void* k_b_r    = d_in[16];
    const void* s_W_r    = d_in[17];
    const void* s_b_r    = d_in[18];
    const void* emb_r    = d_in[19];
    const void* d0_Wih_r = d_in[20];
    const void* d0_Whh_r = d_in[21];
    const void* d0_bih_r = d_in[22];
    const void* d0_bhh_r = d_in[23];
    const void* d1_Wih_r = d_in[24];
    const void* d1_Whh_r = d_in[25];
    const void* d1_bih_r = d_in[26];
    const void* d1_bhh_r = d_in[27];
    const void* pred_W_r = d_in[28];
    const void* pred_b_r = d_in[29];

    char* w = (char*)d_ws;
    size_t off = 0;
    auto alloc = [&](size_t bytes) -> void* {
        void* p = w + off;
        off = (off + bytes + 63) & ~(size_t)63;
        return p;
    };
    int*   flag    = (int*)  alloc(4);
    u16*   fc      = (u16*)  alloc(3932160ull * 2);   // canonical feat
    u16*   cW[4];
    for (int i = 0; i < 4; i++) cW[i] = (u16*)alloc(1048576ull * 2);  // Wih e0,e1,d0,d1
    u16*   cb[8];
    for (int i = 0; i < 8; i++) cb[i] = (u16*)alloc(2048ull * 2);     // bih/bhh pairs
    u16*   cencW   = (u16*)  alloc(262144ull * 2);
    u16*   cqW     = (u16*)  alloc(262144ull * 2);
    u16*   cpredW  = (u16*)  alloc(148992ull * 2);
    u16*   cemb    = (u16*)  alloc(49664ull * 2);
    u16*   cencb   = (u16*)  alloc(512ull * 2);
    u16*   cqb     = (u16*)  alloc(512ull * 2);
    u16*   ckb     = (u16*)  alloc(512ull * 2);
    u16*   csW     = (u16*)  alloc(512ull * 2);
    u16*   csb     = (u16*)  alloc(2);
    u16*   cpredb  = (u16*)  alloc(97ull * 2);
    float* cvr     = (float*)alloc(32ull * 4);
    u16*   featv   = (u16*)  alloc(655360ull * 2);
    float* xpre    = (float*)alloc(2621440ull * 4);   // (1280,2048) f32; kmap aliases later
    u16*   seq0    = (u16*)  alloc(655360ull * 2);
    u16*   seq1    = (u16*)  alloc(655360ull * 2);
    u16*   tok     = (u16*)  alloc(442368ull * 2);
    u16*   seqd0   = (u16*)  alloc(442368ull * 2);
    u16*   Hid     = (u16*)  alloc(442368ull * 2);
    float* holf    = (float*)alloc(16384ull * 4);
    float* qf      = (float*)alloc(442368ull * 4);
    u16*   featP   = (u16*)  alloc(5505024ull * 2);
    u16*   W2      = (u16*)  alloc(2359296ull * 2);
    float* aw      = (float*)alloc(207360ull * 4);
    float* concat  = (float*)alloc(1327104ull * 4);
    _Float16* Wq[4];
    for (int i = 0; i < 4; i++) Wq[i] = (_Float16*)alloc(1048576ull * 2);
    u16*   kmap    = (u16*)xpre;                       // alias: xpre dead before conv_gemm

    // ---- dtype sniff + canonicalize ----
    sniff_k<<<dim3(1), 64, 0, stream>>>(feat_r, flag);
    auto canon = [&](const void* src, u16* dst, int n) {
        canon_k<<<dim3((n + 255) / 256), 256, 0, stream>>>(src, dst, n, flag);
    };
    canon(feat_r, fc, 3932160);
    canon(e0_Wih_r, cW[0], 1048576); canon(e1_Wih_r, cW[1], 1048576);
    canon(d0_Wih_r, cW[2], 1048576); canon(d1_Wih_r, cW[3], 1048576);
    canon(e0_bih_r, cb[0], 2048); canon(e0_bhh_r, cb[1], 2048);
    canon(e1_bih_r, cb[2], 2048); canon(e1_bhh_r, cb[3], 2048);
    canon(d0_bih_r, cb[4], 2048); canon(d0_bhh_r, cb[5], 2048);
    canon(d1_bih_r, cb[6], 2048); canon(d1_bhh_r, cb[7], 2048);
    canon(enc_W_r, cencW, 262144); canon(enc_b_r, cencb, 512);
    canon(q_W_r, cqW, 262144); canon(q_b_r, cqb, 512);
    canon(k_b_r, ckb, 512); canon(s_W_r, csW, 512); canon(s_b_r, csb, 1);
    canon(emb_r, cemb, 49664);
    canon(pred_W_r, cpredW, 148992); canon(pred_b_r, cpredb, 97);
    canonf_k<<<dim3(1), 64, 0, stream>>>(vr_r, cvr, 32, flag);
    w2_k<<<dim3(9216), 256, 0, stream>>>(k_W_r, W2, flag);
    wq_k<<<dim3(512), 256, 0, stream>>>(e0_Whh_r, Wq[0], flag);
    wq_k<<<dim3(512), 256, 0, stream>>>(e1_Whh_r, Wq[1], flag);
    wq_k<<<dim3(512), 256, 0, stream>>>(d0_Whh_r, Wq[2], flag);
    wq_k<<<dim3(512), 256, 0, stream>>>(d1_Whh_r, Wq[3], flag);

    // ---- prep ----
    featv_k  <<<dim3(2560), 256, 0, stream>>>(fc, featv);
    padfeat_k<<<dim3(21504), 256, 0, stream>>>(fc, featP);

    // ---- encoder ----
    gemm_nt_f32<<<dim3(32, 20), 256, 0, stream>>>(featv, 512, cW[0], cb[0], cb[1], xpre, 1280, 2048, 512, 2048);
    lstm_rec<<<dim3(32), 256, 0, stream>>>(xpre, Wq[0], seq0, nullptr, 40, 0);
    gemm_nt_f32<<<dim3(32, 20), 256, 0, stream>>>(seq0, 512, cW[1], cb[2], cb[3], xpre, 1280, 2048, 512, 2048);
    lstm_rec<<<dim3(32), 256, 0, stream>>>(xpre, Wq[1], seq1, nullptr, 40, 0);
    gemm_nt_f32<<<dim3(8, 1), 256, 0, stream>>>(seq1 + 39 * 512, 40 * 512, cencW, cencb, nullptr, holf, 32, 512, 512, 512);

    // ---- decoder ----
    tok_k<<<dim3(1728), 256, 0, stream>>>(holf, cemb, label, tok);
    gemm_nt_f32<<<dim3(32, 14), 256, 0, stream>>>(tok, 512, cW[2], cb[4], cb[5], xpre, 864, 2048, 512, 2048);
    lstm_rec<<<dim3(32), 256, 0, stream>>>(xpre, Wq[2], seqd0, nullptr, 27, 0);
    gemm_nt_f32<<<dim3(32, 14), 256, 0, stream>>>(seqd0, 512, cW[3], cb[6], cb[7], xpre, 864, 2048, 512, 2048);
    lstm_rec<<<dim3(32), 256, 0, stream>>>(xpre, Wq[3], Hid, concat, 27, 1536);

    // ---- attention (xpre dead from here; kmap aliases it) ----
    gemm_nt_f32<<<dim3(8, 14), 256, 0, stream>>>(Hid, 512, cqW, cqb, nullptr, qf, 864, 512, 512, 512);
    conv_gemm<<<dim3(8, 120), 256, 0, stream>>>(featP, W2, ckb, kmap);
    score_k<<<dim3(864), 256, 0, stream>>>(qf, kmap, csW, csb, cvr, aw);
    attn_k<<<dim3(256), 256, 0, stream>>>(fc, aw, concat);
    holfill_k<<<dim3(1728), 256, 0, stream>>>(holf, concat);

    // ---- prediction ----
    pred_k<<<dim3(216), 256, 0, stream>>>(concat, cpredW, cpredb, d_out, flag);
}